// Round 1
// baseline (52.499 us; speedup 1.0000x reference)
//
#include <hip/hip_runtime.h>

#define BATCH 256
#define UNITS 64
#define IFEAT 256
#define OFEAT 256

typedef __attribute__((ext_vector_type(8))) short v8s;   // 8 bf16 (4 VGPRs)
typedef __attribute__((ext_vector_type(4))) float v4f;   // MFMA acc / global f32x4

// fp32 -> bf16 round-to-nearest-even (finite inputs)
static __device__ __forceinline__ unsigned short f2bf(float f) {
    unsigned int x = __float_as_uint(f);
    unsigned int r = x + 0x7fffu + ((x >> 16) & 1u);
    return (unsigned short)(r >> 16);
}

static __device__ __forceinline__ float sigmoid_f(float x) {
    return 1.0f / (1.0f + __expf(-x));
}
static __device__ __forceinline__ float tanh_f(float x) {
    float ax = fabsf(x);
    float e = __expf(-2.0f * ax);
    float t = (1.0f - e) / (1.0f + e);
    return copysignf(t, x);
}

// ---------------------------------------------------------------------------
// Kernel H: hvec[w][u][o] = sum_i hinit[u][i] * w_h{r,z,n}[u][i][o]
// grid = 3*64*2 = 384 blocks, 256 threads. Streams 50.3 MB coalesced.
// ---------------------------------------------------------------------------
__global__ void gru_hvec(const float* __restrict__ whr,
                         const float* __restrict__ whz,
                         const float* __restrict__ whn,
                         const float* __restrict__ hinit,
                         float* __restrict__ hv) {
    __shared__ float red[256];
    const int bid  = blockIdx.x;
    const int half = bid & 1;
    const int u    = (bid >> 1) & 63;
    const int w    = bid >> 7;                     // 0..2
    const float* wh = (w == 0) ? whr : (w == 1) ? whz : whn;

    const int t = threadIdx.x;
    const int o = half * 128 + (t & 127);
    const int c = t >> 7;                          // i-half 0/1
    const float* hp = hinit + u * IFEAT;
    const float* wp = wh + (size_t)u * IFEAT * OFEAT + o;

    float acc = 0.0f;
    const int i0 = c * 128;
#pragma unroll 8
    for (int i = 0; i < 128; ++i) {
        acc += hp[i0 + i] * wp[(size_t)(i0 + i) * OFEAT];
    }
    red[t] = acc;
    __syncthreads();
    if (c == 0) hv[((size_t)w * UNITS + u) * OFEAT + o] = red[t] + red[t + 128];
}

// ---------------------------------------------------------------------------
// Kernel G: fused 3-way MFMA GEMM + GRU epilogue.
// BM=BN=128, BK=32, 512 threads = 8 waves (4m x 2n), wave tile 32x64.
// grid = 64 units * 2 mb * 2 nb = 256 blocks.
// ---------------------------------------------------------------------------
__global__ __launch_bounds__(512, 2) void gru_gemm(
    const float* __restrict__ x,
    const float* __restrict__ wir,
    const float* __restrict__ wiz,
    const float* __restrict__ win,
    const float* __restrict__ hinit,
    const float* __restrict__ hv,
    float* __restrict__ out) {
    // frag-linear LDS: As[buf][kg][row][j], Bs[buf][w][kg][col][j]  (j = k&7)
    __shared__ unsigned short As[2][4][128][8];        // 16 KB
    __shared__ unsigned short Bs[2][3][4][128][8];     // 48 KB

    const int bid = blockIdx.x;
    const int u   = bid >> 2;
    const int mb  = (bid >> 1) & 1;
    const int nb  = bid & 1;
    const int b0  = mb * 128;
    const int o0  = nb * 128;

    const int t    = threadIdx.x;
    const int lane = t & 63;
    const int wave = t >> 6;
    const int wm   = wave >> 1;        // 0..3 (rows)
    const int wn   = wave & 1;         // 0..1 (cols)
    const int lg   = lane >> 4;        // k-group 0..3
    const int lr   = lane & 15;

    // staging assignment
    const int akg  = t & 3;            // A: k-group
    const int arow = t >> 2;           // A: row 0..127
    const int bk   = t >> 4;           // B: k 0..31
    const int bo8  = (t & 15) * 8;     // B: col base 0..120

    const float* wptr0 = wir;
    const float* wptr1 = wiz;
    const float* wptr2 = win;

    const size_t a_base = (size_t)(b0 + arow) * (UNITS * IFEAT) + (size_t)u * IFEAT + akg * 8;
    const size_t b_base = (size_t)u * IFEAT * OFEAT + (size_t)bk * OFEAT + o0 + bo8;

    v4f ra0, ra1;
    v4f rb[3][2];

    auto stage_load = [&](int kk) {
        const float* ap = x + a_base + kk * 32;
        ra0 = *(const v4f*)ap;
        ra1 = *(const v4f*)(ap + 4);
        const size_t boff = b_base + (size_t)kk * 32 * OFEAT;
        rb[0][0] = *(const v4f*)(wptr0 + boff);
        rb[0][1] = *(const v4f*)(wptr0 + boff + 4);
        rb[1][0] = *(const v4f*)(wptr1 + boff);
        rb[1][1] = *(const v4f*)(wptr1 + boff + 4);
        rb[2][0] = *(const v4f*)(wptr2 + boff);
        rb[2][1] = *(const v4f*)(wptr2 + boff + 4);
    };

    auto stage_write = [&](int bb) {
        v8s av;
        av[0] = (short)f2bf(ra0[0]); av[1] = (short)f2bf(ra0[1]);
        av[2] = (short)f2bf(ra0[2]); av[3] = (short)f2bf(ra0[3]);
        av[4] = (short)f2bf(ra1[0]); av[5] = (short)f2bf(ra1[1]);
        av[6] = (short)f2bf(ra1[2]); av[7] = (short)f2bf(ra1[3]);
        *(v8s*)&As[bb][akg][arow][0] = av;
        const int skg = bk >> 3, sj = bk & 7;
#pragma unroll
        for (int w = 0; w < 3; ++w) {
            const v4f q0 = rb[w][0], q1 = rb[w][1];
            Bs[bb][w][skg][bo8 + 0][sj] = f2bf(q0[0]);
            Bs[bb][w][skg][bo8 + 1][sj] = f2bf(q0[1]);
            Bs[bb][w][skg][bo8 + 2][sj] = f2bf(q0[2]);
            Bs[bb][w][skg][bo8 + 3][sj] = f2bf(q0[3]);
            Bs[bb][w][skg][bo8 + 4][sj] = f2bf(q1[0]);
            Bs[bb][w][skg][bo8 + 5][sj] = f2bf(q1[1]);
            Bs[bb][w][skg][bo8 + 6][sj] = f2bf(q1[2]);
            Bs[bb][w][skg][bo8 + 7][sj] = f2bf(q1[3]);
        }
    };

    v4f acc[3][2][4];
#pragma unroll
    for (int w = 0; w < 3; ++w)
#pragma unroll
        for (int mi = 0; mi < 2; ++mi)
#pragma unroll
            for (int ni = 0; ni < 4; ++ni)
                acc[w][mi][ni] = (v4f){0.f, 0.f, 0.f, 0.f};

    stage_load(0);
#pragma unroll 1
    for (int kk = 0; kk < 8; ++kk) {
        const int bb = kk & 1;
        stage_write(bb);               // waits vmcnt via reg deps, ds_writes
        __syncthreads();               // buf ready for all waves
        if (kk < 7) stage_load(kk + 1);  // issue next loads; land under MFMAs

        v8s a0 = *(const v8s*)&As[bb][lg][wm * 32 + lr][0];
        v8s a1 = *(const v8s*)&As[bb][lg][wm * 32 + 16 + lr][0];
#pragma unroll
        for (int w = 0; w < 3; ++w) {
#pragma unroll
            for (int ni = 0; ni < 4; ++ni) {
                v8s b = *(const v8s*)&Bs[bb][w][lg][wn * 64 + ni * 16 + lr][0];
                acc[w][0][ni] = __builtin_amdgcn_mfma_f32_16x16x32_bf16(a0, b, acc[w][0][ni], 0, 0, 0);
                acc[w][1][ni] = __builtin_amdgcn_mfma_f32_16x16x32_bf16(a1, b, acc[w][1][ni], 0, 0, 0);
            }
        }
    }

    // ---- epilogue: GRU combine ----
    // C layout: col = lane&15, row = (lane>>4)*4 + reg
    const int obase = o0 + wn * 64 + lr;
    float hrv[4], hzv[4], hnv[4], h0v[4];
#pragma unroll
    for (int ni = 0; ni < 4; ++ni) {
        const int o = obase + ni * 16;
        hrv[ni] = hv[(0 * UNITS + u) * OFEAT + o];
        hzv[ni] = hv[(1 * UNITS + u) * OFEAT + o];
        hnv[ni] = hv[(2 * UNITS + u) * OFEAT + o];
        h0v[ni] = hinit[u * OFEAT + o];
    }
    const int rbase = b0 + wm * 32 + lg * 4;
#pragma unroll
    for (int mi = 0; mi < 2; ++mi) {
#pragma unroll
        for (int ni = 0; ni < 4; ++ni) {
            const int o = obase + ni * 16;
#pragma unroll
            for (int jj = 0; jj < 4; ++jj) {
                const int b = rbase + mi * 16 + jj;
                const float r = sigmoid_f(acc[0][mi][ni][jj] + hrv[ni]);
                const float z = sigmoid_f(acc[1][mi][ni][jj] + hzv[ni]);
                const float n = tanh_f(acc[2][mi][ni][jj] + r * hnv[ni]);
                out[((size_t)b * UNITS + u) * OFEAT + o] = (1.0f - z) * n + z * h0v[ni];
            }
        }
    }
}

extern "C" void kernel_launch(void* const* d_in, const int* in_sizes, int n_in,
                              void* d_out, int out_size, void* d_ws, size_t ws_size,
                              hipStream_t stream) {
    const float* x     = (const float*)d_in[0];
    const float* w_ir  = (const float*)d_in[1];
    const float* w_iz  = (const float*)d_in[2];
    const float* w_in  = (const float*)d_in[3];
    const float* w_hr  = (const float*)d_in[4];
    const float* w_hz  = (const float*)d_in[5];
    const float* w_hn  = (const float*)d_in[6];
    const float* hinit = (const float*)d_in[7];
    float* out = (float*)d_out;
    float* hv  = (float*)d_ws;   // 3*64*256 floats = 196 KB

    gru_hvec<<<dim3(384), dim3(256), 0, stream>>>(w_hr, w_hz, w_hn, hinit, hv);
    gru_gemm<<<dim3(256), dim3(512), 0, stream>>>(x, w_ir, w_iz, w_in, hinit, hv, out);
}

// Round 2
// 36.977 us; speedup vs baseline: 1.4198x; 1.4198x over previous
//
#include <hip/hip_runtime.h>

#define BATCH 256
#define UNITS 64
#define IFEAT 256
#define OFEAT 256

typedef __attribute__((ext_vector_type(8))) short v8s;   // 8 bf16 (4 VGPRs)
typedef __attribute__((ext_vector_type(4))) float v4f;   // MFMA acc / global f32x4

// fp32 -> bf16 round-to-nearest-even (finite inputs)
static __device__ __forceinline__ unsigned short f2bf(float f) {
    unsigned int x = __float_as_uint(f);
    unsigned int r = x + 0x7fffu + ((x >> 16) & 1u);
    return (unsigned short)(r >> 16);
}

static __device__ __forceinline__ float sigmoid_f(float x) {
    return 1.0f / (1.0f + __expf(-x));
}
static __device__ __forceinline__ float tanh_f(float x) {
    float ax = fabsf(x);
    float e = __expf(-2.0f * ax);
    float t = (1.0f - e) / (1.0f + e);
    return copysignf(t, x);
}

// ---------------------------------------------------------------------------
// Kernel H: hvec[w][u][o] = sum_i hinit[u][i] * w_h{r,z,n}[u][i][o]
// grid = 3*64*2 = 384 blocks, 256 threads. Streams 50.3 MB coalesced (~8us).
// ---------------------------------------------------------------------------
__global__ void gru_hvec(const float* __restrict__ whr,
                         const float* __restrict__ whz,
                         const float* __restrict__ whn,
                         const float* __restrict__ hinit,
                         float* __restrict__ hv) {
    __shared__ float red[256];
    const int bid  = blockIdx.x;
    const int half = bid & 1;
    const int u    = (bid >> 1) & 63;
    const int w    = bid >> 7;                     // 0..2
    const float* wh = (w == 0) ? whr : (w == 1) ? whz : whn;

    const int t = threadIdx.x;
    const int o = half * 128 + (t & 127);
    const int c = t >> 7;                          // i-half 0/1
    const float* hp = hinit + u * IFEAT;
    const float* wp = wh + (size_t)u * IFEAT * OFEAT + o;

    float acc = 0.0f;
    const int i0 = c * 128;
#pragma unroll 8
    for (int i = 0; i < 128; ++i) {
        acc += hp[i0 + i] * wp[(size_t)(i0 + i) * OFEAT];
    }
    red[t] = acc;
    __syncthreads();
    if (c == 0) hv[((size_t)w * UNITS + u) * OFEAT + o] = red[t] + red[t + 128];
}

// ---------------------------------------------------------------------------
// Kernel G: fused 3-way MFMA GEMM + GRU epilogue.
// BM=BN=64, BK=32, 256 threads = 4 waves (2m x 2n), wave tile 32x32.
// grid = 1024 blocks (64u x 4mb x 4nb), XCD-swizzled so a unit's 16 blocks
// share one XCD's L2. B transpose done in registers: each thread loads one
// W column (8 k, stride-1KB dwords, col=lane so coalesced per wave) and does
// ONE conflict-free ds_write_b128. Double-buffered LDS, 1 barrier/K-step.
// ---------------------------------------------------------------------------
__global__ __launch_bounds__(256, 3) void gru_gemm(
    const float* __restrict__ x,
    const float* __restrict__ wir,
    const float* __restrict__ wiz,
    const float* __restrict__ win,
    const float* __restrict__ hinit,
    const float* __restrict__ hv,
    float* __restrict__ out) {
    // frag-linear LDS: As[buf][kg][row][j], Bs[buf][g][kg][col][j] (j = k&7)
    __shared__ unsigned short As[2][4][64][8];         // 8 KB
    __shared__ unsigned short Bs[2][3][4][64][8];      // 24 KB

    const int bid = blockIdx.x;
    // XCD swizzle: u % 8 == bid % 8  -> all 16 blocks of a unit on one XCD
    const int u   = (bid & 7) + 8 * ((bid >> 3) >> 4);
    const int rem = (bid >> 3) & 15;
    const int b0  = (rem >> 2) * 64;       // batch tile
    const int o0  = (rem & 3) * 64;        // output-feature tile

    const int t    = threadIdx.x;
    const int lane = t & 63;
    const int wave = t >> 6;
    const int wm   = wave >> 1;            // 0/1
    const int wn   = wave & 1;             // 0/1
    const int lg   = lane >> 4;            // k-quad 0..3
    const int lr   = lane & 15;

    // staging assignment: col/row = lane (coalesced + conflict-free), kg = wave
    const int srow = t & 63;
    const int skg  = t >> 6;

    const size_t a_gbase = (size_t)(b0 + srow) * (UNITS * IFEAT)
                         + (size_t)u * IFEAT + skg * 8;
    const size_t b_gbase = (size_t)u * (IFEAT * OFEAT)
                         + (size_t)(skg * 8) * OFEAT + o0 + srow;

    v4f ra0, ra1;
    float rb0[8], rb1[8], rb2[8];

    auto stage_load = [&](int kk) {
        const float* ap = x + a_gbase + kk * 32;
        ra0 = *(const v4f*)ap;
        ra1 = *(const v4f*)(ap + 4);
        const size_t bo = b_gbase + (size_t)kk * 32 * OFEAT;
#pragma unroll
        for (int j = 0; j < 8; ++j) rb0[j] = wir[bo + (size_t)j * OFEAT];
#pragma unroll
        for (int j = 0; j < 8; ++j) rb1[j] = wiz[bo + (size_t)j * OFEAT];
#pragma unroll
        for (int j = 0; j < 8; ++j) rb2[j] = win[bo + (size_t)j * OFEAT];
    };

    auto stage_write = [&](int bb) {
        v8s av;
        av[0] = (short)f2bf(ra0[0]); av[1] = (short)f2bf(ra0[1]);
        av[2] = (short)f2bf(ra0[2]); av[3] = (short)f2bf(ra0[3]);
        av[4] = (short)f2bf(ra1[0]); av[5] = (short)f2bf(ra1[1]);
        av[6] = (short)f2bf(ra1[2]); av[7] = (short)f2bf(ra1[3]);
        *(v8s*)&As[bb][skg][srow][0] = av;
        v8s bv0, bv1, bv2;
#pragma unroll
        for (int j = 0; j < 8; ++j) bv0[j] = (short)f2bf(rb0[j]);
#pragma unroll
        for (int j = 0; j < 8; ++j) bv1[j] = (short)f2bf(rb1[j]);
#pragma unroll
        for (int j = 0; j < 8; ++j) bv2[j] = (short)f2bf(rb2[j]);
        *(v8s*)&Bs[bb][0][skg][srow][0] = bv0;
        *(v8s*)&Bs[bb][1][skg][srow][0] = bv1;
        *(v8s*)&Bs[bb][2][skg][srow][0] = bv2;
    };

    v4f acc[3][2][2];
#pragma unroll
    for (int g = 0; g < 3; ++g)
#pragma unroll
        for (int mi = 0; mi < 2; ++mi)
#pragma unroll
            for (int ni = 0; ni < 2; ++ni)
                acc[g][mi][ni] = (v4f){0.f, 0.f, 0.f, 0.f};

    stage_load(0);
    stage_write(0);            // prologue: full latency exposed once
    stage_load(1);
    __syncthreads();

#pragma unroll 2
    for (int kk = 0; kk < 8; ++kk) {
        const int bb = kk & 1;
        if (kk < 7) stage_write(bb ^ 1);   // data for kk+1 into other buffer
        if (kk < 6) stage_load(kk + 2);    // refill regs; lands under MFMAs

        v8s a0 = *(const v8s*)&As[bb][lg][wm * 32 + lr][0];
        v8s a1 = *(const v8s*)&As[bb][lg][wm * 32 + 16 + lr][0];
#pragma unroll
        for (int g = 0; g < 3; ++g) {
#pragma unroll
            for (int ni = 0; ni < 2; ++ni) {
                v8s b = *(const v8s*)&Bs[bb][g][lg][wn * 32 + ni * 16 + lr][0];
                acc[g][0][ni] = __builtin_amdgcn_mfma_f32_16x16x32_bf16(a0, b, acc[g][0][ni], 0, 0, 0);
                acc[g][1][ni] = __builtin_amdgcn_mfma_f32_16x16x32_bf16(a1, b, acc[g][1][ni], 0, 0, 0);
            }
        }
        if (kk < 7) __syncthreads();       // writes(bb^1) visible, reads(bb) done
    }

    // ---- epilogue: GRU combine ----
    // C layout: col = lane&15, row = (lane>>4)*4 + reg
    const int obase = o0 + wn * 32 + lr;
    float hrv[2], hzv[2], hnv[2], h0v[2];
#pragma unroll
    for (int ni = 0; ni < 2; ++ni) {
        const int o = obase + ni * 16;
        hrv[ni] = hv[(0 * UNITS + u) * OFEAT + o];
        hzv[ni] = hv[(1 * UNITS + u) * OFEAT + o];
        hnv[ni] = hv[(2 * UNITS + u) * OFEAT + o];
        h0v[ni] = hinit[u * OFEAT + o];
    }
    const int rbase = b0 + wm * 32 + lg * 4;
#pragma unroll
    for (int mi = 0; mi < 2; ++mi) {
#pragma unroll
        for (int ni = 0; ni < 2; ++ni) {
            const int o = obase + ni * 16;
#pragma unroll
            for (int jj = 0; jj < 4; ++jj) {
                const int row = rbase + mi * 16 + jj;
                const float r = sigmoid_f(acc[0][mi][ni][jj] + hrv[ni]);
                const float z = sigmoid_f(acc[1][mi][ni][jj] + hzv[ni]);
                const float n = tanh_f(acc[2][mi][ni][jj] + r * hnv[ni]);
                out[((size_t)row * UNITS + u) * OFEAT + o] = (1.0f - z) * n + z * h0v[ni];
            }
        }
    }
}

extern "C" void kernel_launch(void* const* d_in, const int* in_sizes, int n_in,
                              void* d_out, int out_size, void* d_ws, size_t ws_size,
                              hipStream_t stream) {
    const float* x     = (const float*)d_in[0];
    const float* w_ir  = (const float*)d_in[1];
    const float* w_iz  = (const float*)d_in[2];
    const float* w_in  = (const float*)d_in[3];
    const float* w_hr  = (const float*)d_in[4];
    const float* w_hz  = (const float*)d_in[5];
    const float* w_hn  = (const float*)d_in[6];
    const float* hinit = (const float*)d_in[7];
    float* out = (float*)d_out;
    float* hv  = (float*)d_ws;   // 3*64*256 floats

    gru_hvec<<<dim3(384), dim3(256), 0, stream>>>(w_hr, w_hz, w_hn, hinit, hv);
    gru_gemm<<<dim3(1024), dim3(256), 0, stream>>>(x, w_ir, w_iz, w_in, hinit, hv, out);
}